// Round 3
// baseline (170.505 us; speedup 1.0000x reference)
//
#include <hip/hip_runtime.h>
#include <hip/hip_bf16.h>

// Pinball loss: mean over all elements of max((q-1)*(t-p), q*(t-p)), q = quantiles[0].
// preds, target: [128,512,288] f32 (18,874,368 elems each). Output: 1 f32 scalar.
// Memory-bound streaming reduction.
//   R1: unroll x4 grid-stride (8 outstanding loads/wave, was 2 -> latency-bound),
//       single kernel + per-block atomicAdd (was 2 launches, ~115us overhead gap).
//   R2: identical resubmit — R1 bench died on GPUAcquisitionTimeout (infra).

#define BLOCK 256
#define GRID  2048

__device__ __forceinline__ float pin4(float4 t, float4 p, float q, float qm1) {
    float e0 = t.x - p.x;
    float e1 = t.y - p.y;
    float e2 = t.z - p.z;
    float e3 = t.w - p.w;
    return fmaxf(qm1 * e0, q * e0) + fmaxf(qm1 * e1, q * e1)
         + fmaxf(qm1 * e2, q * e2) + fmaxf(qm1 * e3, q * e3);
}

__global__ __launch_bounds__(BLOCK) void pinball_kernel(
    const float* __restrict__ preds,
    const float* __restrict__ target,
    const float* __restrict__ quantiles,
    float* __restrict__ out,       // [1], pre-zeroed by memset
    int n,                         // total element count
    float inv_n)
{
    const float q   = quantiles[0];
    const float qm1 = q - 1.0f;

    const int n4     = n >> 2;                         // float4 count
    const int idx    = blockIdx.x * BLOCK + threadIdx.x;
    const int stride = gridDim.x * BLOCK;

    const float4* __restrict__ p4 = (const float4*)preds;
    const float4* __restrict__ t4 = (const float4*)target;

    float acc0 = 0.0f, acc1 = 0.0f, acc2 = 0.0f, acc3 = 0.0f;

    int i = idx;
    // main loop: 8 independent loads in flight per iteration
    for (; i < n4 - 3 * stride; i += 4 * stride) {
        float4 pa = p4[i];
        float4 pb = p4[i +     stride];
        float4 pc = p4[i + 2 * stride];
        float4 pd = p4[i + 3 * stride];
        float4 ta = t4[i];
        float4 tb = t4[i +     stride];
        float4 tc = t4[i + 2 * stride];
        float4 td = t4[i + 3 * stride];
        acc0 += pin4(ta, pa, q, qm1);
        acc1 += pin4(tb, pb, q, qm1);
        acc2 += pin4(tc, pc, q, qm1);
        acc3 += pin4(td, pd, q, qm1);
    }
    // float4 tail
    for (; i < n4; i += stride) {
        acc0 += pin4(t4[i], p4[i], q, qm1);
    }
    // scalar tail (n % 4 != 0 — not hit for this shape, but safe)
    for (int j = (n4 << 2) + idx; j < n; j += stride) {
        float e = target[j] - preds[j];
        acc0 += fmaxf(qm1 * e, q * e);
    }

    float acc = (acc0 + acc1) + (acc2 + acc3);

    // wave64 butterfly reduce
    #pragma unroll
    for (int off = 32; off > 0; off >>= 1)
        acc += __shfl_down(acc, off, 64);

    __shared__ float s[BLOCK / 64];
    const int lane = threadIdx.x & 63;
    const int wid  = threadIdx.x >> 6;
    if (lane == 0) s[wid] = acc;
    __syncthreads();
    if (threadIdx.x == 0) {
        float b = (s[0] + s[1]) + (s[2] + s[3]);
        atomicAdd(out, b * inv_n);   // device-scope; 2048 adds total
    }
}

extern "C" void kernel_launch(void* const* d_in, const int* in_sizes, int n_in,
                              void* d_out, int out_size, void* d_ws, size_t ws_size,
                              hipStream_t stream) {
    const float* preds     = (const float*)d_in[0];
    const float* target    = (const float*)d_in[1];
    const float* quantiles = (const float*)d_in[2];
    float*       out       = (float*)d_out;

    const int n = in_sizes[0];
    const float inv_n = 1.0f / (float)n;

    hipMemsetAsync(out, 0, sizeof(float), stream);   // d_out is poisoned 0xAA
    pinball_kernel<<<GRID, BLOCK, 0, stream>>>(preds, target, quantiles, out, n, inv_n);
}